// Round 1
// baseline (2771.807 us; speedup 1.0000x reference)
//
#include <hip/hip_runtime.h>
#include <math.h>

#define BB 32
#define NN 1024
#define KK 20
static constexpr float EPSF = 1e-5f;

// ---------------- transpose (B,N,C) -> (B,C,N) ----------------
template<int C>
__global__ void transpose_kernel(const float* __restrict__ x, float* __restrict__ xT) {
  int t = blockIdx.x * blockDim.x + threadIdx.x;
  if (t >= BB * NN) return;
  int b = t >> 10, i = t & (NN - 1);
  #pragma unroll
  for (int c = 0; c < C; ++c)
    xT[((size_t)b * C + c) * NN + i] = x[(size_t)t * C + c];
}

// ---------------- xx = sum(x*x) per point ----------------
template<int C>
__global__ void xx_kernel(const float* __restrict__ x, float* __restrict__ xx) {
  int t = blockIdx.x * blockDim.x + threadIdx.x;
  if (t >= BB * NN) return;
  const float* p = x + (size_t)t * C;
  float s = 0.f;
  #pragma unroll
  for (int c = 0; c < C; ++c) s += p[c] * p[c];
  xx[t] = s;
}

// ---------------- knn: one block per (b,i), top-K by pd = 2*dot - xxi - xxj ----------------
template<int C>
__global__ __launch_bounds__(256) void knn_kernel(
    const float* __restrict__ x,   // (B,N,C) row-major (for xi)
    const float* __restrict__ xT,  // (B,C,N)
    const float* __restrict__ xx,  // (B,N)
    int* __restrict__ oidx) {      // (B,N,K)
  int bi = blockIdx.x;
  int b = bi >> 10, i = bi & (NN - 1);

  float xi[C];
  const float* xrow = x + (size_t)bi * C;
  #pragma unroll
  for (int c = 0; c < C; ++c) xi[c] = xrow[c];

  const float* xTb = xT + (size_t)b * C * NN;
  const float* xxb = xx + (size_t)b * NN;
  float xxi = xxb[i];

  __shared__ float dist[NN];
  int j0 = threadIdx.x * 4;
  float d0 = 0.f, d1 = 0.f, d2 = 0.f, d3 = 0.f;
  #pragma unroll
  for (int c = 0; c < C; ++c) {
    float4 v = *(const float4*)(xTb + (size_t)c * NN + j0);
    d0 += xi[c] * v.x; d1 += xi[c] * v.y; d2 += xi[c] * v.z; d3 += xi[c] * v.w;
  }
  float4 xv = *(const float4*)(xxb + j0);
  dist[j0 + 0] = 2.f * d0 - xxi - xv.x;
  dist[j0 + 1] = 2.f * d1 - xxi - xv.y;
  dist[j0 + 2] = 2.f * d2 - xxi - xv.z;
  dist[j0 + 3] = 2.f * d3 - xxi - xv.w;
  __syncthreads();

  __shared__ float rv[4];
  __shared__ int   ri[4];
  int lane = threadIdx.x & 63, wid = threadIdx.x >> 6;
  int* orow = oidx + (size_t)bi * KK;

  for (int kk = 0; kk < KK; ++kk) {
    float4 dv = *(const float4*)&dist[j0];
    float bv = -INFINITY; int bj = NN;
    // ascending j within thread: strict > keeps lowest index on ties
    if (dv.x > bv) { bv = dv.x; bj = j0 + 0; }
    if (dv.y > bv) { bv = dv.y; bj = j0 + 1; }
    if (dv.z > bv) { bv = dv.z; bj = j0 + 2; }
    if (dv.w > bv) { bv = dv.w; bj = j0 + 3; }
    #pragma unroll
    for (int off = 32; off > 0; off >>= 1) {
      float ov = __shfl_down(bv, off);
      int   oj = __shfl_down(bj, off);
      if (ov > bv || (ov == bv && oj < bj)) { bv = ov; bj = oj; }
    }
    if (lane == 0) { rv[wid] = bv; ri[wid] = bj; }
    __syncthreads();
    if (threadIdx.x == 0) {
      float fv = rv[0]; int fj = ri[0];
      #pragma unroll
      for (int w = 1; w < 4; ++w)
        if (rv[w] > fv || (rv[w] == fv && ri[w] < fj)) { fv = rv[w]; fj = ri[w]; }
      orow[kk] = fj;
      dist[fj] = -INFINITY;
    }
    __syncthreads();
  }
}

// ---------------- fused gather + edgeconv + BN/ReLU + max over k ----------------
// dot = wA . nbr + (wB - wA) . ctr ;  y = max_k relu(dot*s + bias)
template<int C, int O>
__global__ __launch_bounds__(256) void edge_kernel(
    const float* __restrict__ x,     // (B,N,C)
    const int*   __restrict__ idx,   // (B,N,K)
    const float* __restrict__ w,     // (O,2C)
    const float* __restrict__ g,
    const float* __restrict__ bb,
    float* __restrict__ y,           // (B,N,O)
    float* __restrict__ yT) {        // (B,O,N) or nullptr
  constexpr int NPB = 256 / O;
  int b = blockIdx.y;
  int i0 = blockIdx.x * NPB;
  int o = threadIdx.x % O;
  int p = threadIdx.x / O;
  int i = i0 + p;

  __shared__ float xi[NPB][C];
  __shared__ float nbr[NPB][KK][C];
  __shared__ int   sidx[NPB][KK];

  for (int t = threadIdx.x; t < NPB * KK; t += 256)
    sidx[t / KK][t % KK] = idx[((size_t)b * NN + i0 + t / KK) * KK + (t % KK)];
  for (int t = threadIdx.x; t < NPB * C; t += 256)
    xi[t / C][t % C] = x[((size_t)b * NN + i0 + t / C) * C + (t % C)];
  __syncthreads();

  if constexpr (C % 4 == 0) {
    constexpr int C4 = C / 4;
    const float4* x4 = (const float4*)x;
    float4* n4 = (float4*)&nbr[0][0][0];
    for (int t = threadIdx.x; t < NPB * KK * C4; t += 256) {
      int r = t / C4, c4 = t % C4;
      int pp = r / KK, kk = r % KK;
      int j = sidx[pp][kk];
      n4[t] = x4[((size_t)b * NN + j) * C4 + c4];
    }
  } else {
    for (int t = threadIdx.x; t < NPB * KK * C; t += 256) {
      int r = t / C, cc = t % C;
      int pp = r / KK, kk = r % KK;
      int j = sidx[pp][kk];
      nbr[pp][kk][cc] = x[((size_t)b * NN + j) * C + cc];
    }
  }
  __syncthreads();

  float s = g[o] / sqrtf(1.0f + EPSF);
  float bias = bb[o];
  const float* wrow = w + (size_t)o * 2 * C;
  float m = 0.0f;

  if constexpr (C % 4 == 0) {
    constexpr int C4 = C / 4;
    float4 wa[C4];
    const float4* w4 = (const float4*)wrow;
    #pragma unroll
    for (int c4 = 0; c4 < C4; ++c4) wa[c4] = w4[c4];
    float c0 = 0.f;
    const float4* xi4 = (const float4*)&xi[p][0];
    const float4* wb4 = (const float4*)(wrow + C);
    #pragma unroll
    for (int c4 = 0; c4 < C4; ++c4) {
      float4 wb = wb4[c4], xv = xi4[c4], a = wa[c4];
      c0 += (wb.x - a.x) * xv.x + (wb.y - a.y) * xv.y +
            (wb.z - a.z) * xv.z + (wb.w - a.w) * xv.w;
    }
    for (int k = 0; k < KK; ++k) {
      const float4* nv = (const float4*)&nbr[p][k][0];
      float d = c0;
      #pragma unroll
      for (int c4 = 0; c4 < C4; ++c4) {
        float4 v = nv[c4], a = wa[c4];
        d += a.x * v.x + a.y * v.y + a.z * v.z + a.w * v.w;
      }
      m = fmaxf(m, fmaxf(d * s + bias, 0.0f));
    }
  } else {
    float wa[C];
    float c0 = 0.f;
    #pragma unroll
    for (int c = 0; c < C; ++c) { wa[c] = wrow[c]; c0 += (wrow[C + c] - wa[c]) * xi[p][c]; }
    for (int k = 0; k < KK; ++k) {
      float d = c0;
      #pragma unroll
      for (int c = 0; c < C; ++c) d += wa[c] * nbr[p][k][c];
      m = fmaxf(m, fmaxf(d * s + bias, 0.0f));
    }
  }

  y[((size_t)b * NN + i) * O + o] = m;
  if (yT) yT[((size_t)b * O + o) * NN + i] = m;
}

// ---------------- global max pool over N ----------------
template<int O>
__global__ __launch_bounds__(256) void pool_kernel(
    const float* __restrict__ y, float* __restrict__ pooled, int ooff) {
  int b = blockIdx.x;
  int ob = blockIdx.y * 64;
  int lane = threadIdx.x & 63, wv = threadIdx.x >> 6;
  int o = ob + lane;
  const float* yb = y + (size_t)b * NN * O;
  float m = -INFINITY;
  for (int i = wv; i < NN; i += 4)
    m = fmaxf(m, yb[(size_t)i * O + o]);
  __shared__ float red[4][64];
  red[wv][lane] = m;
  __syncthreads();
  if (wv == 0) {
    m = fmaxf(fmaxf(red[0][lane], red[1][lane]), fmaxf(red[2][lane], red[3][lane]));
    pooled[b * 320 + ooff + o] = m;
  }
}

// ---------------- fc: out[b,o] = act((in[b]·W[o] + lb[o])*s + bb[o]) ----------------
template<int IN, int OUT, bool BNRELU>
__global__ void fc_kernel(const float* __restrict__ in, const float* __restrict__ W,
                          const float* __restrict__ lb, const float* __restrict__ g,
                          const float* __restrict__ bbias, float* __restrict__ out) {
  int t = blockIdx.x * blockDim.x + threadIdx.x;
  if (t >= BB * OUT) return;
  int b = t / OUT, o = t % OUT;
  const float4* iv = (const float4*)(in + (size_t)b * IN);
  const float4* wv = (const float4*)(W + (size_t)o * IN);
  float acc = 0.f;
  for (int c4 = 0; c4 < IN / 4; ++c4) {
    float4 a = iv[c4], ww = wv[c4];
    acc += a.x * ww.x + a.y * ww.y + a.z * ww.z + a.w * ww.w;
  }
  acc += lb[o];
  if (BNRELU) {
    float s = g[o] / sqrtf(1.0f + EPSF);
    acc = fmaxf(acc * s + bbias[o], 0.0f);
  }
  out[t] = acc;
}

extern "C" void kernel_launch(void* const* d_in, const int* in_sizes, int n_in,
                              void* d_out, int out_size, void* d_ws, size_t ws_size,
                              hipStream_t stream) {
  const float* x   = (const float*)d_in[0];
  const float* w1  = (const float*)d_in[1];
  const float* g1  = (const float*)d_in[2];
  const float* b1  = (const float*)d_in[3];
  const float* w2  = (const float*)d_in[4];
  const float* g2  = (const float*)d_in[5];
  const float* b2  = (const float*)d_in[6];
  const float* w3  = (const float*)d_in[7];
  const float* g3  = (const float*)d_in[8];
  const float* b3  = (const float*)d_in[9];
  const float* w4  = (const float*)d_in[10];
  const float* g4  = (const float*)d_in[11];
  const float* b4  = (const float*)d_in[12];
  const float* lw1 = (const float*)d_in[13];
  const float* lb1 = (const float*)d_in[14];
  const float* g5  = (const float*)d_in[15];
  const float* b5  = (const float*)d_in[16];
  const float* lw2 = (const float*)d_in[17];
  const float* lb2 = (const float*)d_in[18];
  const float* g6  = (const float*)d_in[19];
  const float* b6  = (const float*)d_in[20];
  const float* lw3 = (const float*)d_in[21];
  const float* lb3 = (const float*)d_in[22];
  float* out = (float*)d_out;

  char* ws = (char*)d_ws;
  size_t off = 0;
  auto alloc = [&](size_t bytes) -> char* {
    char* p = ws + off;
    off += (bytes + 255) & ~255ULL;
    return p;
  };
  int*   idx    = (int*)  alloc((size_t)BB * NN * KK * 4);
  float* xx     = (float*)alloc((size_t)BB * NN * 4);
  float* xT0    = (float*)alloc((size_t)BB * 3 * NN * 4);
  float* bufA   = (float*)alloc((size_t)BB * NN * 64 * 4);
  float* bufAT  = (float*)alloc((size_t)BB * 64 * NN * 4);
  float* bufB   = (float*)alloc((size_t)BB * NN * 64 * 4);
  float* bufBT  = (float*)alloc((size_t)BB * 64 * NN * 4);
  float* bufC   = (float*)alloc((size_t)BB * NN * 128 * 4);
  float* pooled = (float*)alloc((size_t)BB * 320 * 4);
  float* h1     = (float*)alloc((size_t)BB * 1024 * 4);
  float* h2     = (float*)alloc((size_t)BB * 512 * 4);

  dim3 blk(256);
  int bn_blocks = (BB * NN + 255) / 256;

  // ---- layer 1 (C=3 -> 64) ----
  transpose_kernel<3><<<bn_blocks, blk, 0, stream>>>(x, xT0);
  xx_kernel<3><<<bn_blocks, blk, 0, stream>>>(x, xx);
  knn_kernel<3><<<BB * NN, blk, 0, stream>>>(x, xT0, xx, idx);
  edge_kernel<3, 64><<<dim3(NN / 4, BB), blk, 0, stream>>>(x, idx, w1, g1, b1, bufA, bufAT);
  pool_kernel<64><<<dim3(BB, 1), blk, 0, stream>>>(bufA, pooled, 0);

  // ---- layer 2 (64 -> 64) ----
  xx_kernel<64><<<bn_blocks, blk, 0, stream>>>(bufA, xx);
  knn_kernel<64><<<BB * NN, blk, 0, stream>>>(bufA, bufAT, xx, idx);
  edge_kernel<64, 64><<<dim3(NN / 4, BB), blk, 0, stream>>>(bufA, idx, w2, g2, b2, bufB, bufBT);
  pool_kernel<64><<<dim3(BB, 1), blk, 0, stream>>>(bufB, pooled, 64);

  // ---- layer 3 (64 -> 64) ----
  xx_kernel<64><<<bn_blocks, blk, 0, stream>>>(bufB, xx);
  knn_kernel<64><<<BB * NN, blk, 0, stream>>>(bufB, bufBT, xx, idx);
  edge_kernel<64, 64><<<dim3(NN / 4, BB), blk, 0, stream>>>(bufB, idx, w3, g3, b3, bufA, bufAT);
  pool_kernel<64><<<dim3(BB, 1), blk, 0, stream>>>(bufA, pooled, 128);

  // ---- layer 4 (64 -> 128) ----
  xx_kernel<64><<<bn_blocks, blk, 0, stream>>>(bufA, xx);
  knn_kernel<64><<<BB * NN, blk, 0, stream>>>(bufA, bufAT, xx, idx);
  edge_kernel<64, 128><<<dim3(NN / 2, BB), blk, 0, stream>>>(bufA, idx, w4, g4, b4, bufC, nullptr);
  pool_kernel<128><<<dim3(BB, 2), blk, 0, stream>>>(bufC, pooled, 192);

  // ---- classifier ----
  fc_kernel<320, 1024, true><<<(BB * 1024 + 255) / 256, blk, 0, stream>>>(pooled, lw1, lb1, g5, b5, h1);
  fc_kernel<1024, 512, true><<<(BB * 512 + 255) / 256, blk, 0, stream>>>(h1, lw2, lb2, g6, b6, h2);
  fc_kernel<512, 40, false><<<(BB * 40 + 255) / 256, blk, 0, stream>>>(h2, lw3, lb3, nullptr, nullptr, out);
}